// Round 18
// baseline (1669.836 us; speedup 1.0000x reference)
//
#include <hip/hip_runtime.h>
#include <hip/hip_bf16.h>

#define LAYERS 4
#define H 1024
#define NH 16
#define KVH 4
#define HD 64
#define KVD 256
#define FF 4096
#define VOC 32000
#define BB 2
#define SS 2048
#define MROWS (BB*SS)
#define QKVN 1536

typedef __attribute__((ext_vector_type(4))) float f32x4;
typedef __attribute__((ext_vector_type(8))) short short8;
typedef __attribute__((ext_vector_type(4))) unsigned short u16x4;
typedef __attribute__((ext_vector_type(8))) unsigned short u16x8;
typedef __attribute__((ext_vector_type(2))) unsigned int u32x2;

__device__ inline unsigned short f2bf(float f){
  union { float f; unsigned u; } v; v.f = f;
  return (unsigned short)((v.u + 0x7FFFu + ((v.u >> 16) & 1u)) >> 16);
}
__device__ inline float bf2f(unsigned short u){
  union { unsigned u; float f; } v; v.u = ((unsigned)u) << 16;
  return v.f;
}
__device__ inline unsigned cvt_pk_bf16(float a, float b){
  unsigned r;
  asm("v_cvt_pk_bf16_f32 %0, %1, %2" : "=v"(r) : "v"(a), "v"(b));
  return r;
}

// ---------------- embedding: x(bf16) = tok[id] + pos[s] ----------------
__global__ __launch_bounds__(256) void embed_kernel(const int* __restrict__ ids,
    const float* __restrict__ tok, const float* __restrict__ pos, unsigned short* __restrict__ x)
{
  int row = blockIdx.x;
  int s = row & (SS-1);
  int id = ids[row];
  int t = threadIdx.x;
  f32x4 a = *(const f32x4*)&tok[(size_t)id*H + t*4];
  f32x4 p = *(const f32x4*)&pos[(size_t)s*H + t*4];
  u16x4 o;
  #pragma unroll
  for (int i=0;i<4;i++) o[i] = f2bf(a[i] + p[i]);
  *(u16x4*)&x[(size_t)row*H + t*4] = o;
}

// ---------------- layernorm: bf16 in -> bf16 out ----------------
__global__ __launch_bounds__(256) void ln_kernel(const unsigned short* __restrict__ x,
    const float* __restrict__ g, const float* __restrict__ b, unsigned short* __restrict__ out)
{
  int row = blockIdx.x;
  int t = threadIdx.x;
  u16x4 v4 = *(const u16x4*)&x[(size_t)row*H + t*4];
  float v[4];
  #pragma unroll
  for (int i=0;i<4;i++) v[i] = bf2f(v4[i]);
  float s  = v[0]+v[1]+v[2]+v[3];
  float s2 = v[0]*v[0]+v[1]*v[1]+v[2]*v[2]+v[3]*v[3];
  #pragma unroll
  for (int off=1; off<64; off<<=1){ s += __shfl_xor(s,off); s2 += __shfl_xor(s2,off); }
  __shared__ float red[8];
  int w = t>>6;
  if ((t&63)==0){ red[w]=s; red[4+w]=s2; }
  __syncthreads();
  float S1 = red[0]+red[1]+red[2]+red[3];
  float S2 = red[4]+red[5]+red[6]+red[7];
  float mean = S1 * (1.0f/H);
  float var  = S2 * (1.0f/H) - mean*mean;
  float rs = rsqrtf(var + 1e-5f);
  u16x4 o;
  #pragma unroll
  for (int i=0;i<4;i++) o[i] = f2bf((v[i]-mean)*rs*g[t*4+i] + b[t*4+i]);
  *(u16x4*)&out[(size_t)row*H + t*4] = o;
}

// ---------------- split-K reduce: x += p0 + p1 + bias (bf16 residual) ----------------
__global__ __launch_bounds__(256) void red2_kernel(const float* __restrict__ p0,
    const float* __restrict__ p1, const float* __restrict__ bias, unsigned short* __restrict__ x)
{
  size_t base = (size_t)blockIdx.x * H + threadIdx.x*4;
  f32x4 a = *(const f32x4*)&p0[base];
  f32x4 b = *(const f32x4*)&p1[base];
  u16x4 xr = *(const u16x4*)&x[base];
  f32x4 bi = *(const f32x4*)&bias[threadIdx.x*4];
  u16x4 o;
  #pragma unroll
  for (int i=0;i<4;i++) o[i] = f2bf(a[i] + b[i] + bi[i] + bf2f(xr[i]));
  *(u16x4*)&x[base] = o;
}

// ---------------- weight convert+transpose: f32 [K][N] -> bf16 [N][K] ----------------
__global__ __launch_bounds__(256) void convT_kernel(const float* __restrict__ in,
    unsigned short* __restrict__ out, int K, int N, size_t istride, size_t ostride)
{
  __shared__ float ts[64][65];
  in  += (size_t)blockIdx.z * istride;
  out += (size_t)blockIdx.z * ostride;
  int n0 = blockIdx.x*64, k0 = blockIdx.y*64;
  int rx = threadIdx.x & 15, ry = threadIdx.x >> 4;
  #pragma unroll
  for (int j=0;j<4;j++){
    int kk = ry + j*16;
    f32x4 v = *(const f32x4*)&in[(size_t)(k0+kk)*N + n0 + rx*4];
    ts[kk][rx*4+0] = v[0]; ts[kk][rx*4+1] = v[1];
    ts[kk][rx*4+2] = v[2]; ts[kk][rx*4+3] = v[3];
  }
  __syncthreads();
  int wx = threadIdx.x & 7, wy = threadIdx.x >> 3;
  #pragma unroll
  for (int j=0;j<2;j++){
    int n = wy + j*32;
    u16x8 o;
    #pragma unroll
    for (int e=0;e<8;e++) o[e] = f2bf(ts[wx*8+e][n]);
    *(u16x8*)&out[(size_t)(n0+n)*K + k0 + wx*8] = o;
  }
}

// ---------------- bias concat for fused QKV ----------------
__global__ __launch_bounds__(256) void bcat_kernel(const float* __restrict__ bq,
    const float* __restrict__ bk, const float* __restrict__ bv, float* __restrict__ out)
{
  int l = blockIdx.x, t = threadIdx.x;
  #pragma unroll
  for (int i=0;i<4;i++) out[l*QKVN + t + i*256] = bq[l*H + t + i*256];
  out[l*QKVN + 1024 + t] = bk[l*KVD + t];
  out[l*QKVN + 1280 + t] = bv[l*KVD + t];
}

// ---------------- GEMM 128x128, 8 WAVES (512 thr), BK=32, deep pipeline ----------------
// K = loop-K (per slice), Kstride = row stride; blockIdx.z selects k-slice.
// EPI: 1 = +bias+residual(bf16) -> bf16 | 5 = fused QKV | 6 = f32 partial (split-K)
template<int EPI>
__global__ __launch_bounds__(512, 4) void gemm_bt(
    const unsigned short* __restrict__ A, const unsigned short* __restrict__ Bt,
    const float* __restrict__ bias, const unsigned short* __restrict__ resb,
    unsigned short* __restrict__ outb,
    unsigned short* __restrict__ outb2, unsigned short* __restrict__ outb3,
    float* __restrict__ outfp, int N, int K, int Kstride)
{
  __shared__ __align__(16) char lds[65536];   // 4 bufs x (A 8K + B 8K)
  const int tid = threadIdx.x;
  const int lane = tid & 63, wid = tid >> 6;
  const int wr = (wid>>2)*64, wc = (wid&3)*32;
  const int fr = lane & 15, fq = lane >> 4;
  const int m0 = blockIdx.x*128, n0 = blockIdx.y*128;
  const int nt = K >> 5;
  const size_t kofs = (size_t)blockIdx.z * K;
  A  += kofs;
  Bt += kofs;
  f32x4 acc[4][2] = {};

  #define STG1(PTR, baserow, kt, ldsoff) do {                                   \
    int rr = tid>>2;                                                            \
    int ss = (tid&3) ^ ((rr>>1)&3);                                             \
    __builtin_amdgcn_global_load_lds(                                           \
      (const __attribute__((address_space(1))) void*)((PTR) + (size_t)((baserow)+rr)*Kstride + (kt)*32 + ss*8), \
      (__attribute__((address_space(3))) void*)(lds + (ldsoff) + wid*1024), 16, 0, 0); \
  } while(0)
  #define RDA1(buf,row) (*(const short8*)(lds + (buf)*16384 + (row)*64 + ((fq ^ (((row)>>1)&3))*16)))
  #define RDB1(buf,row) (*(const short8*)(lds + (buf)*16384 + 8192 + (row)*64 + ((fq ^ (((row)>>1)&3))*16)))

  STG1(A,  m0, 0, 0);      STG1(Bt, n0, 0, 8192);
  STG1(A,  m0, 1, 16384);  STG1(Bt, n0, 1, 16384+8192);
  STG1(A,  m0, 2, 32768);  STG1(Bt, n0, 2, 32768+8192);
  asm volatile("s_waitcnt vmcnt(4)" ::: "memory");
  __builtin_amdgcn_s_barrier();

  short8 a[4], b[2];
  #pragma unroll
  for (int mi=0;mi<4;mi++) a[mi] = RDA1(0, wr+mi*16+fr);
  b[0] = RDB1(0, wc+fr);
  b[1] = RDB1(0, wc+16+fr);

  for (int t = 0; t < nt; ++t){
    const int s3 = (t+3) & 3;
    const int nb = (t+1) & 3;
    const int t3 = (t+3 < nt) ? t+3 : nt-1;
    STG1(A,  m0, t3, s3*16384);
    STG1(Bt, n0, t3, s3*16384+8192);
    __builtin_amdgcn_s_setprio(1);
    #pragma unroll
    for (int mi=0;mi<4;mi++)
      acc[mi][0] = __builtin_amdgcn_mfma_f32_16x16x32_bf16(a[mi], b[0], acc[mi][0], 0,0,0);
    __builtin_amdgcn_s_setprio(0);
    asm volatile("s_waitcnt lgkmcnt(0)" ::: "memory");
    asm volatile("s_waitcnt vmcnt(4)" ::: "memory");
    __builtin_amdgcn_s_barrier();
    short8 na[4], nb0, nb1;
    nb0 = RDB1(nb, wc+fr);
    nb1 = RDB1(nb, wc+16+fr);
    #pragma unroll
    for (int mi=0;mi<4;mi++) na[mi] = RDA1(nb, wr+mi*16+fr);
    __builtin_amdgcn_s_setprio(1);
    #pragma unroll
    for (int mi=0;mi<4;mi++)
      acc[mi][1] = __builtin_amdgcn_mfma_f32_16x16x32_bf16(a[mi], b[1], acc[mi][1], 0,0,0);
    __builtin_amdgcn_s_setprio(0);
    b[0] = nb0; b[1] = nb1;
    #pragma unroll
    for (int mi=0;mi<4;mi++) a[mi] = na[mi];
  }
  #undef STG1
  #undef RDA1
  #undef RDB1

  float* outz = outfp;
  if (EPI==6) outz = outfp + (size_t)blockIdx.z * ((size_t)gridDim.x*128) * N;
  #pragma unroll
  for (int mi=0;mi<4;mi++)
    #pragma unroll
    for (int ni=0;ni<2;ni++){
      int col = n0 + wc + ni*16 + fr;
      float bi = (EPI==6) ? 0.0f : bias[col];
      #pragma unroll
      for (int r=0;r<4;r++){
        int row = m0 + wr + mi*16 + fq*4 + r;
        float vv = acc[mi][ni][r] + bi;
        if (EPI==1){
          size_t idx = (size_t)row*N + col;
          outb[idx] = f2bf(vv + bf2f(resb[idx]));
        } else if (EPI==6){
          outz[(size_t)row*N + col] = vv;
        } else {  // EPI==5
          if (col < 1024)      outb [(size_t)row*H + col]            = f2bf(vv);
          else if (col < 1280) outb2[(size_t)row*KVD + (col-1024)]   = f2bf(vv);
          else                 outb3[(size_t)(col-1280)*MROWS + row] = f2bf(vv);
        }
      }
    }
}

// ---------------- GEMM 256x256, 8 waves, BK=32, 16x16 MFMA, 4-sub-phase pipeline ----
// (r11 variant — best measured)
// EPI: 2 = +bias+gelu -> bf16 | 3 = plain -> f32
template<int EPI>
__global__ __launch_bounds__(512, 2) void gemm256(
    const unsigned short* __restrict__ A, const unsigned short* __restrict__ Bt,
    const float* __restrict__ bias, float* __restrict__ outf,
    unsigned short* __restrict__ outb, int N, int K)
{
  __shared__ __align__(16) char lds[131072];  // 4 bufs x (A 16K + B 16K)
  const int tid = threadIdx.x;
  const int lane = tid & 63, wid = tid >> 6;
  const int wrr = wid >> 2, wc = wid & 3;
  const int fr = lane & 15, fq = lane >> 4;
  const int m0 = blockIdx.x*256, n0 = blockIdx.y*256;
  const int nt = K >> 5;
  f32x4 acc[8][4] = {};

  #define STG(PTR, baserow, kt, ldsoff) do {                                    \
    _Pragma("unroll")                                                           \
    for (int c=0;c<2;c++){                                                      \
      int rr = c*128 + (tid>>2);                                                \
      int ss = (tid&3) ^ ((rr>>1)&3);                                           \
      __builtin_amdgcn_global_load_lds(                                         \
        (const __attribute__((address_space(1))) void*)((PTR) + (size_t)((baserow)+rr)*K + (kt)*32 + ss*8), \
        (__attribute__((address_space(3))) void*)(lds + (ldsoff) + c*8192 + wid*1024), 16, 0, 0); \
    }                                                                           \
  } while(0)
  #define RDA(buf,row) (*(const short8*)(lds + (buf)*32768 + (row)*64 + ((fq ^ (((row)>>1)&3))*16)))
  #define RDB(buf,row) (*(const short8*)(lds + (buf)*32768 + 16384 + (row)*64 + ((fq ^ (((row)>>1)&3))*16)))

  STG(A,  m0, 0, 0);      STG(Bt, n0, 0, 16384);
  STG(A,  m0, 1, 32768);  STG(Bt, n0, 1, 32768+16384);
  STG(A,  m0, 2, 65536);  STG(Bt, n0, 2, 65536+16384);
  asm volatile("s_waitcnt vmcnt(8)" ::: "memory");
  __builtin_amdgcn_s_barrier();

  short8 a[4], b2[2];
  short8 bA = RDB(0, wc*64+fr);
  short8 bB = RDB(0, wc*64+16+fr);
  #pragma unroll
  for (int mi=0;mi<4;mi++) a[mi] = RDA(0, wrr*128+mi*16+fr);

  for (int t = 0; t < nt; ++t){
    const int buf = t & 3;
    const int s3 = (t+3) & 3;
    const int nb = (t+1) & 3;
    const int t3 = (t+3 < nt) ? t+3 : nt-1;
    short8 ah[4];
    #pragma unroll
    for (int mi=0;mi<4;mi++) ah[mi] = RDA(buf, wrr*128+(4+mi)*16+fr);
    b2[0] = RDB(buf, wc*64+32+fr);
    b2[1] = RDB(buf, wc*64+48+fr);
    STG(A, m0, t3, s3*32768);
    __builtin_amdgcn_s_setprio(1);
    #pragma unroll
    for (int mi=0;mi<4;mi++){
      acc[mi][0] = __builtin_amdgcn_mfma_f32_16x16x32_bf16(a[mi], bA, acc[mi][0], 0,0,0);
      acc[mi][1] = __builtin_amdgcn_mfma_f32_16x16x32_bf16(a[mi], bB, acc[mi][1], 0,0,0);
    }
    __builtin_amdgcn_s_setprio(0);
    STG(Bt, n0, t3, s3*32768+16384);
    __builtin_amdgcn_s_setprio(1);
    #pragma unroll
    for (int mi=0;mi<4;mi++){
      acc[4+mi][0] = __builtin_amdgcn_mfma_f32_16x16x32_bf16(ah[mi], bA, acc[4+mi][0], 0,0,0);
      acc[4+mi][1] = __builtin_amdgcn_mfma_f32_16x16x32_bf16(ah[mi], bB, acc[4+mi][1], 0,0,0);
    }
    __builtin_amdgcn_s_setprio(0);
    asm volatile("s_waitcnt lgkmcnt(0)" ::: "memory");
    asm volatile("s_waitcnt vmcnt(8)" ::: "memory");
    __builtin_amdgcn_s_barrier();
    short8 nbA = RDB(nb, wc*64+fr);
    short8 nbB = RDB(nb, wc*64+16+fr);
    short8 na[4];
    #pragma unroll
    for (int mi=0;mi<4;mi++) na[mi] = RDA(nb, wrr*128+mi*16+fr);
    __builtin_amdgcn_s_setprio(1);
    #pragma unroll
    for (int mi=0;mi<4;mi++){
      acc[mi][2] = __builtin_amdgcn_mfma_f32_16x16x32_bf16(a[mi], b2[0], acc[mi][2], 0,0,0);
      acc[mi][3] = __builtin_amdgcn_mfma_f32_16x16x32_bf16(a[mi], b2[1], acc[mi][3], 0,0,0);
    }
    __builtin_amdgcn_s_setprio(0);
    __builtin_amdgcn_s_setprio(1);
    #pragma unroll
    for (int mi=0;mi<4;mi++){
      acc[4+mi][2] = __builtin_amdgcn_mfma_f32_16x16x32_bf16(ah[mi], b2[0], acc[4+mi][2], 0,0,0);
      acc[4+mi][3] = __builtin_amdgcn_mfma_f32_16x16x32_bf16(ah[mi], b2[1], acc[4+mi][3], 0,0,0);
    }
    __builtin_amdgcn_s_setprio(0);
    bA = nbA; bB = nbB;
    #pragma unroll
    for (int mi=0;mi<4;mi++) a[mi] = na[mi];
  }
  #undef STG
  #undef RDA
  #undef RDB

  #pragma unroll
  for (int mi=0; mi<8; mi++)
    #pragma unroll
    for (int ni=0; ni<4; ni++){
      int col = n0 + wc*64 + ni*16 + fr;
      float bi = (EPI==3) ? 0.0f : bias[col];
      #pragma unroll
      for (int r=0; r<4; r++){
        int row = m0 + wrr*128 + mi*16 + fq*4 + r;
        float vv = acc[mi][ni][r] + bi;
        size_t idx = (size_t)row*N + col;
        if (EPI==3) outf[idx] = vv;
        else        outb[idx] = f2bf(0.5f*vv*(1.0f+erff(vv*0.70710678118f)));
      }
    }
}

// ---------------- flash attention v4 ----------------
#define LOG2E 1.4426950408889634f
__global__ __launch_bounds__(256) void attn_kernel(
    const unsigned short* __restrict__ q, const unsigned short* __restrict__ kptr,
    const unsigned short* __restrict__ vt, const float* __restrict__ mask,
    unsigned short* __restrict__ o)
{
  __shared__ char Pbuf[4][4096];
  int tid = threadIdx.x;
  int lane = tid & 63, wid = tid >> 6;
  int fr = lane & 15, fq = lane >> 4, fo = fq*8;
  int h = blockIdx.y, b = blockIdx.z, g = h >> 2;
  int qcol = h*HD, kcol = g*HD;
  int qbase = b*SS + blockIdx.x*128 + wid*32;
  char* Pl = Pbuf[wid];
  int swz = (fr & 7) << 4;

  short8 bq[2][2];
  #pragma unroll
  for (int h2=0; h2<2; h2++){
    const unsigned short* qrow = q + (size_t)(qbase + h2*16 + fr)*H + qcol;
    bq[h2][0] = *(const short8*)(qrow + fo);
    bq[h2][1] = *(const short8*)(qrow + 32 + fo);
  }

  f32x4 oacc[2][4] = {};
  float mrun[2] = {-1e30f, -1e30f}, lsum[2] = {0.f, 0.f};
  const float sc2 = 0.125f * LOG2E;

  const unsigned short* kp[4];
  #pragma unroll
  for (int f=0; f<4; f++) kp[f] = kptr + (size_t)(b*SS + f*16 + fr)*KVD + kcol + fo;
  const unsigned short* vp[4];
  #pragma unroll
  for (int dc=0; dc<4; dc++) vp[dc] = vt + (size_t)(kcol + dc*16 + fr)*MROWS + b*SS + fo;
  const float* mp = mask + b*SS + fq*4;

  short8 kaA[4][2], kaB[4][2];
  #pragma unroll
  for (int f=0; f<4; f++){
    kaA[f][0] = *(const short8*)(kp[f]);
    kaA[f][1] = *(const short8*)(kp[f] + 32);
    kp[f] += 64*KVD;
  }

#define ATTN_STEP(KA, KB, PF) do {                                             \
    f32x4 mkv[4];                                                              \
    _Pragma("unroll")                                                          \
    for (int f=0; f<4; f++) mkv[f] = *(const f32x4*)(mp + f*16);               \
    short8 va[4][2];                                                           \
    _Pragma("unroll")                                                          \
    for (int dc=0; dc<4; dc++){                                                \
      va[dc][0] = *(const short8*)(vp[dc]);                                    \
      va[dc][1] = *(const short8*)(vp[dc] + 32);                               \
    }                                                                          \
    f32x4 sf[2][4] = {};                                                       \
    __builtin_amdgcn_s_setprio(1);                                             \
    _Pragma("unroll")                                                          \
    for (int h2=0; h2<2; h2++)                                                 \
      _Pragma("unroll")                                                        \
      for (int f=0; f<4; f++){                                                 \
        sf[h2][f] = __builtin_amdgcn_mfma_f32_16x16x32_bf16(KA[f][0], bq[h2][0], sf[h2][f],0,0,0); \
        sf[h2][f] = __builtin_amdgcn_mfma_f32_16x16x32_bf16(KA[f][1], bq[h2][1], sf[h2][f],0,0,0); \
      }                                                                        \
    __builtin_amdgcn_s_setprio(0);                                             \
    if (PF){                                                                   \
      _Pragma("unroll")                                                        \
      for (int f=0; f<4; f++){                                                 \
        KB[f][0] = *(const short8*)(kp[f]);                                    \
        KB[f][1] = *(const short8*)(kp[f] + 32);                               \
        kp[f] += 64*KVD;                                                       \
      }                                                                        \
    }                                                                          \
    _Pragma("unroll")                                                          \
    for (int f=0; f<4; f++){                                                   \
      _Pragma("unroll")                                                        \
      for (int r=0; r<4; r++){                                                 \
        float m2 = mkv[f][r]*LOG2E;                                            \
        sf[0][f][r] = sf[0][f][r]*sc2 + m2;                                    \
        sf[1][f][r] = sf[1][f][r]*sc2 + m2;                                    \
      }                                                                        \
    }                                                                          \
    float pm[2];                                                               \
    _Pragma("unroll")                                                          \
    for (int h2=0; h2<2; h2++){                                                \
      float a0 = fmaxf(fmaxf(sf[h2][0][0],sf[h2][0][1]), fmaxf(sf[h2][0][2],sf[h2][0][3])); \
      float a1 = fmaxf(fmaxf(sf[h2][1][0],sf[h2][1][1]), fmaxf(sf[h2][1][2],sf[h2][1][3])); \
      float a2 = fmaxf(fmaxf(sf[h2][2][0],sf[h2][2][1]), fmaxf(sf[h2][2][2],sf[h2][2][3])); \
      float a3 = fmaxf(fmaxf(sf[h2][3][0],sf[h2][3][1]), fmaxf(sf[h2][3][2],sf[h2][3][3])); \
      float p = fmaxf(fmaxf(a0,a1), fmaxf(a2,a3));                             \
      p = fmaxf(p, __shfl_xor(p, 16));                                         \
      p = fmaxf(p, __shfl_xor(p, 32));                                         \
      pm[h2] = p;                                                              \
    }                                                                          \
    if (!__all(pm[0] <= mrun[0]+8.f && pm[1] <= mrun[1]+8.f)){                 \
      float al[2];                                                             \
      _Pragma("unroll")                                                        \
      for (int h2=0; h2<2; h2++){                                              \
        float mn = fmaxf(mrun[h2], pm[h2]);                                    \
        al[h2] = __builtin_amdgcn_exp2f(mrun[h2]-mn);                          \
        mrun[h2] = mn;                                                         \
        lsum[h2] *= al[h2];                                                    \
      }                                                                        \
      _Pragma("unroll")                                                        \
      for (int r=0; r<4; r++){                                                 \
        float altl = __shfl(al[0], fq*4+r);                                    \
        float alth = __shfl(al[1], fq*4+r);                                    \
        _Pragma("unroll")                                                      \
        for (int dc=0; dc<4; dc++){ oacc[0][dc][r]*=altl; oacc[1][dc][r]*=alth; } \
      }                                                                        \
    }                                                                          \
    _Pragma("unroll")                                                          \
    for (int h2=0; h2<2; h2++){                                                \
      float ps = 0.f;                                                          \
      _Pragma("unroll")                                                        \
      for (int f=0; f<4; f++)                                                  \
        _Pragma("unroll")                                                      \
        for (int r=0; r<4; r++){                                               \
          float e = __builtin_amdgcn_exp2f(sf[h2][f][r]-mrun[h2]);             \
          sf[h2][f][r] = e; ps += e;                                           \
        }                                                                      \
      ps += __shfl_xor(ps, 16);                                                \
      ps += __shfl_xor(ps, 32);                                                \
      lsum[h2] += ps;                                                          \
    }                                                                          \
    _Pragma("unroll")                                                          \
    for (int h2=0; h2<2; h2++){                                                \
      int prow = h2*16 + fr;                                                   \
      _Pragma("unroll")                                                        \
      for (int f=0; f<4; f++){                                                 \
        u32x2 pw;                                                              \
        pw[0] = cvt_pk_bf16(sf[h2][f][0], sf[h2][f][1]);                       \
        pw[1] = cvt_pk_bf16(sf[h2][f][2], sf[h2][f][3]);                       \
        *(u32x2*)(Pl + prow*128 + ((f*32 + fq*8) ^ swz)) = pw;                 \
      }                                                                        \
    }                                                                          \
    __builtin_amdgcn_s_setprio(1);                                             \
    _Pragma("unroll")                                                          \
    for (int h2=0; h2<2; h2++){                                                \
      int prow = h2*16 + fr;                                                   \
      _Pragma("unroll")                                                        \
      for (int gs=0; gs<2; gs++){                                              \
        short8 pa = *(const short8*)(Pl + prow*128 + ((gs*64 + fq*16) ^ swz)); \
        _Pragma("unroll")                                                      \
        for (int dc=0; dc<4; dc++)                                             \
          oacc[h2][dc] = __builtin_amdgcn_mfma_f32_16x16x32_bf16(pa, va[dc][gs], oacc[h2][dc],0,0,0); \
      }                                                                        \
    }                                                                          \
    __builtin_amdgcn_s_setprio(0);                                             \
    _Pragma("unroll")                                                          \
    for (int dc=0; dc<4; dc++) vp[dc] += 64;                                   \
    mp += 64;                                                                  \
  } while(0)

  for (int it = 0; it < SS/128 - 1; ++it){
    ATTN_STEP(kaA, kaB, 1);
    ATTN_STEP(kaB, kaA, 1);
  }
  ATTN_STEP(kaA, kaB, 1);
  ATTN_STEP(kaB, kaA, 0);
#undef ATTN_STEP

  #pragma unroll
  for (int h2=0; h2<2; h2++){
    float lt[4];
    #pragma unroll
    for (int r=0; r<4; r++) lt[r] = __shfl(lsum[h2], fq*4+r);
    #pragma unroll
    for (int dc=0; dc<4; dc++)
      #pragma unroll
      for (int r=0; r<4; r++){
        int row = qbase + h2*16 + fq*4 + r;
        o[(size_t)row*H + qcol + dc*16 + fr] = f2bf(oacc[h2][dc][r] / lt[r]);
      }
  }
}

extern "C" void kernel_launch(void* const* d_in, const int* in_sizes, int n_in,
                              void* d_out, int out_size, void* d_ws, size_t ws_size,
                              hipStream_t stream)
{
  const int*   ids  = (const int*)  d_in[0];
  const float* mask = (const float*)d_in[1];
  const float* tok  = (const float*)d_in[2];
  const float* pos  = (const float*)d_in[3];
  const float* Wq   = (const float*)d_in[4];
  const float* bq   = (const float*)d_in[5];
  const float* Wk   = (const float*)d_in[6];
  const float* bk   = (const float*)d_in[7];
  const float* Wv   = (const float*)d_in[8];
  const float* bv   = (const float*)d_in[9];
  const float* Wo   = (const float*)d_in[10];
  const float* bo   = (const float*)d_in[11];
  const float* W1   = (const float*)d_in[12];
  const float* b1   = (const float*)d_in[13];
  const float* W2   = (const float*)d_in[14];
  const float* b2   = (const float*)d_in[15];
  const float* ln1g = (const float*)d_in[16];
  const float* ln1b = (const float*)d_in[17];
  const float* ln2g = (const float*)d_in[18];
  const float* ln2b = (const float*)d_in[19];
  const float* lnfg = (const float*)d_in[20];
  const float* lnfb = (const float*)d_in[21];
  const float* Wh   = (const float*)d_in[22];
  float* out = (float*)d_out;

  char* ws = (char*)d_ws;
  unsigned short* x    = (unsigned short*)ws; ws += (size_t)MROWS*H*2;
  unsigned short* hb   = (unsigned short*)ws; ws += (size_t)MROWS*H*2;
  unsigned short* qb   = (unsigned short*)ws; ws += (size_t)MROWS*H*2;
  unsigned short* kb   = (unsigned short*)ws; ws += (size_t)MROWS*KVD*2;
  unsigned short* vtb  = (unsigned short*)ws; ws += (size_t)KVD*MROWS*2;
  unsigned short* ob   = (unsigned short*)ws; ws += (size_t)MROWS*H*2;
  unsigned short* f1   = (unsigned short*)ws; ws += (size_t)MROWS*FF*2;
  unsigned short* Wqkv = (unsigned short*)ws; ws += (size_t)LAYERS*QKVN*H*2;
  unsigned short* WoT  = (unsigned short*)ws; ws += (size_t)LAYERS*H*H*2;
  unsigned short* W1T  = (unsigned short*)ws; ws += (size_t)LAYERS*H*FF*2;
  unsigned short* W2T  = (unsigned short*)ws; ws += (size_t)LAYERS*H*FF*2;
  unsigned short* WhT  = (unsigned short*)ws; ws += (size_t)H*VOC*2;
  float*          pbuf = (float*)ws;          ws += (size_t)2*MROWS*H*4;
  float*          bcat = (float*)ws;          ws += (size_t)LAYERS*QKVN*4;

  convT_kernel<<<dim3(H/64,   H/64,  LAYERS), 256, 0, stream>>>(Wq, Wqkv,          H,  H,   (size_t)H*H,   (size_t)QKVN*H);
  convT_kernel<<<dim3(KVD/64, H/64,  LAYERS), 256, 0, stream>>>(Wk, Wqkv + 1024*H, H,  KVD, (size_t)H*KVD, (size_t)QKVN*H);
  convT_kernel<<<dim3(KVD/64, H/64,  LAYERS), 256, 0, stream>>>(Wv, Wqkv + 1280*H, H,  KVD, (size_t)H*KVD, (size_t)QKVN*H);
  convT_kernel<<<dim3(H/64,   H/64,  LAYERS), 256, 0, stream>>>(Wo, WoT,           H,  H,   (size_t)H*H,   (size_t)H*H);
  convT_kernel<<<dim3(FF/64,  H/64,  LAYERS), 256, 0, stream>>>(W1, W1T,           H,  FF,  (size_t)H*FF,  (size_t)H*FF);
  convT_kernel<<<dim3(H/64,   FF/64, LAYERS), 256, 0, stream>>>(W2, W2T,           FF, H,   (size_t)FF*H,  (size_t)FF*H);
  convT_kernel<<<dim3(VOC/64, H/64,  1),      256, 0, stream>>>(Wh, WhT,           H,  VOC, 0, 0);
  bcat_kernel<<<LAYERS, 256, 0, stream>>>(bq, bk, bv, bcat);

  embed_kernel<<<MROWS, 256, 0, stream>>>(ids, tok, pos, x);
  for (int l=0; l<LAYERS; l++){
    ln_kernel<<<MROWS,256,0,stream>>>(x, ln1g + l*H, ln1b + l*H, hb);
    gemm_bt<5><<<dim3(MROWS/128, QKVN/128),512,0,stream>>>(hb, Wqkv + (size_t)l*QKVN*H, bcat + l*QKVN, nullptr, qb, kb, vtb, nullptr, QKVN, H, H);
    attn_kernel<<<dim3(SS/128, NH, BB), 256, 0, stream>>>(qb, kb, vtb, mask, ob);
    gemm_bt<1><<<dim3(MROWS/128, H/128),  512,0,stream>>>(ob, WoT + (size_t)l*H*H,  bo + l*H,  x, x, nullptr, nullptr, nullptr, H, H, H);
    ln_kernel<<<MROWS,256,0,stream>>>(x, ln2g + l*H, ln2b + l*H, hb);
    gemm256<2><<<dim3(MROWS/256, FF/256), 512,0,stream>>>(hb, W1T + (size_t)l*H*FF, b1 + l*FF, nullptr, f1, FF, H);
    gemm_bt<6><<<dim3(MROWS/128, H/128, 2), 512,0,stream>>>(f1, W2T + (size_t)l*H*FF, nullptr, nullptr, nullptr, nullptr, nullptr, pbuf, H, FF/2, FF);
    red2_kernel<<<MROWS, 256, 0, stream>>>(pbuf, pbuf + (size_t)MROWS*H, b2 + l*H, x);
  }
  ln_kernel<<<MROWS,256,0,stream>>>(x, lnfg, lnfb, hb);
  gemm256<3><<<dim3(MROWS/256, VOC/256), 512,0,stream>>>(hb, WhT, nullptr, out, nullptr, VOC, H);
}

// Round 19
// 1641.525 us; speedup vs baseline: 1.0172x; 1.0172x over previous
//
#include <hip/hip_runtime.h>
#include <hip/hip_bf16.h>

#define LAYERS 4
#define H 1024
#define NH 16
#define KVH 4
#define HD 64
#define KVD 256
#define FF 4096
#define VOC 32000
#define BB 2
#define SS 2048
#define MROWS (BB*SS)
#define QKVN 1536

typedef __attribute__((ext_vector_type(4))) float f32x4;
typedef __attribute__((ext_vector_type(8))) short short8;
typedef __attribute__((ext_vector_type(4))) unsigned short u16x4;
typedef __attribute__((ext_vector_type(8))) unsigned short u16x8;
typedef __attribute__((ext_vector_type(2))) unsigned int u32x2;

__device__ inline unsigned short f2bf(float f){
  union { float f; unsigned u; } v; v.f = f;
  return (unsigned short)((v.u + 0x7FFFu + ((v.u >> 16) & 1u)) >> 16);
}
__device__ inline float bf2f(unsigned short u){
  union { unsigned u; float f; } v; v.u = ((unsigned)u) << 16;
  return v.f;
}
__device__ inline unsigned cvt_pk_bf16(float a, float b){
  unsigned r;
  asm("v_cvt_pk_bf16_f32 %0, %1, %2" : "=v"(r) : "v"(a), "v"(b));
  return r;
}

// ---------------- embedding: x(bf16) = tok[id] + pos[s] ----------------
__global__ __launch_bounds__(256) void embed_kernel(const int* __restrict__ ids,
    const float* __restrict__ tok, const float* __restrict__ pos, unsigned short* __restrict__ x)
{
  int row = blockIdx.x;
  int s = row & (SS-1);
  int id = ids[row];
  int t = threadIdx.x;
  f32x4 a = *(const f32x4*)&tok[(size_t)id*H + t*4];
  f32x4 p = *(const f32x4*)&pos[(size_t)s*H + t*4];
  u16x4 o;
  #pragma unroll
  for (int i=0;i<4;i++) o[i] = f2bf(a[i] + p[i]);
  *(u16x4*)&x[(size_t)row*H + t*4] = o;
}

// ---------------- layernorm: bf16 in -> bf16 out ----------------
__global__ __launch_bounds__(256) void ln_kernel(const unsigned short* __restrict__ x,
    const float* __restrict__ g, const float* __restrict__ b, unsigned short* __restrict__ out)
{
  int row = blockIdx.x;
  int t = threadIdx.x;
  u16x4 v4 = *(const u16x4*)&x[(size_t)row*H + t*4];
  float v[4];
  #pragma unroll
  for (int i=0;i<4;i++) v[i] = bf2f(v4[i]);
  float s  = v[0]+v[1]+v[2]+v[3];
  float s2 = v[0]*v[0]+v[1]*v[1]+v[2]*v[2]+v[3]*v[3];
  #pragma unroll
  for (int off=1; off<64; off<<=1){ s += __shfl_xor(s,off); s2 += __shfl_xor(s2,off); }
  __shared__ float red[8];
  int w = t>>6;
  if ((t&63)==0){ red[w]=s; red[4+w]=s2; }
  __syncthreads();
  float S1 = red[0]+red[1]+red[2]+red[3];
  float S2 = red[4]+red[5]+red[6]+red[7];
  float mean = S1 * (1.0f/H);
  float var  = S2 * (1.0f/H) - mean*mean;
  float rs = rsqrtf(var + 1e-5f);
  u16x4 o;
  #pragma unroll
  for (int i=0;i<4;i++) o[i] = f2bf((v[i]-mean)*rs*g[t*4+i] + b[t*4+i]);
  *(u16x4*)&out[(size_t)row*H + t*4] = o;
}

// ---------------- weight convert+transpose: f32 [K][N] -> bf16 [N][K] ----------------
__global__ __launch_bounds__(256) void convT_kernel(const float* __restrict__ in,
    unsigned short* __restrict__ out, int K, int N, size_t istride, size_t ostride)
{
  __shared__ float ts[64][65];
  in  += (size_t)blockIdx.z * istride;
  out += (size_t)blockIdx.z * ostride;
  int n0 = blockIdx.x*64, k0 = blockIdx.y*64;
  int rx = threadIdx.x & 15, ry = threadIdx.x >> 4;
  #pragma unroll
  for (int j=0;j<4;j++){
    int kk = ry + j*16;
    f32x4 v = *(const f32x4*)&in[(size_t)(k0+kk)*N + n0 + rx*4];
    ts[kk][rx*4+0] = v[0]; ts[kk][rx*4+1] = v[1];
    ts[kk][rx*4+2] = v[2]; ts[kk][rx*4+3] = v[3];
  }
  __syncthreads();
  int wx = threadIdx.x & 7, wy = threadIdx.x >> 3;
  #pragma unroll
  for (int j=0;j<2;j++){
    int n = wy + j*32;
    u16x8 o;
    #pragma unroll
    for (int e=0;e<8;e++) o[e] = f2bf(ts[wx*8+e][n]);
    *(u16x8*)&out[(size_t)(n0+n)*K + k0 + wx*8] = o;
  }
}

// ---------------- bias concat for fused QKV ----------------
__global__ __launch_bounds__(256) void bcat_kernel(const float* __restrict__ bq,
    const float* __restrict__ bk, const float* __restrict__ bv, float* __restrict__ out)
{
  int l = blockIdx.x, t = threadIdx.x;
  #pragma unroll
  for (int i=0;i<4;i++) out[l*QKVN + t + i*256] = bq[l*H + t + i*256];
  out[l*QKVN + 1024 + t] = bk[l*KVD + t];
  out[l*QKVN + 1280 + t] = bv[l*KVD + t];
}

// ---------------- GEMM 128x128, 8 WAVES (512 thr), BK=32, deep pipeline ----------------
// r13 structure (best measured family config). EPI 1: bf16 residual in/out.
// EPI: 1 = +bias+residual(bf16) -> bf16 | 5 = fused QKV (q / k / v-transposed)
template<int EPI>
__global__ __launch_bounds__(512, 4) void gemm_bt(
    const unsigned short* __restrict__ A, const unsigned short* __restrict__ Bt,
    const float* __restrict__ bias, const unsigned short* __restrict__ resb,
    unsigned short* __restrict__ outb,
    unsigned short* __restrict__ outb2, unsigned short* __restrict__ outb3, int N, int K)
{
  __shared__ __align__(16) char lds[65536];   // 4 bufs x (A 8K + B 8K)
  const int tid = threadIdx.x;
  const int lane = tid & 63, wid = tid >> 6;
  const int wr = (wid>>2)*64, wc = (wid&3)*32;
  const int fr = lane & 15, fq = lane >> 4;
  const int m0 = blockIdx.x*128, n0 = blockIdx.y*128;
  const int nt = K >> 5;
  f32x4 acc[4][2] = {};

  #define STG1(PTR, baserow, kt, ldsoff) do {                                   \
    int rr = tid>>2;                                                            \
    int ss = (tid&3) ^ ((rr>>1)&3);                                             \
    __builtin_amdgcn_global_load_lds(                                           \
      (const __attribute__((address_space(1))) void*)((PTR) + (size_t)((baserow)+rr)*K + (kt)*32 + ss*8), \
      (__attribute__((address_space(3))) void*)(lds + (ldsoff) + wid*1024), 16, 0, 0); \
  } while(0)
  #define RDA1(buf,row) (*(const short8*)(lds + (buf)*16384 + (row)*64 + ((fq ^ (((row)>>1)&3))*16)))
  #define RDB1(buf,row) (*(const short8*)(lds + (buf)*16384 + 8192 + (row)*64 + ((fq ^ (((row)>>1)&3))*16)))

  STG1(A,  m0, 0, 0);      STG1(Bt, n0, 0, 8192);
  STG1(A,  m0, 1, 16384);  STG1(Bt, n0, 1, 16384+8192);
  STG1(A,  m0, 2, 32768);  STG1(Bt, n0, 2, 32768+8192);
  asm volatile("s_waitcnt vmcnt(4)" ::: "memory");
  __builtin_amdgcn_s_barrier();

  short8 a[4], b[2];
  #pragma unroll
  for (int mi=0;mi<4;mi++) a[mi] = RDA1(0, wr+mi*16+fr);
  b[0] = RDB1(0, wc+fr);
  b[1] = RDB1(0, wc+16+fr);

  for (int t = 0; t < nt; ++t){
    const int s3 = (t+3) & 3;
    const int nb = (t+1) & 3;
    const int t3 = (t+3 < nt) ? t+3 : nt-1;
    STG1(A,  m0, t3, s3*16384);
    STG1(Bt, n0, t3, s3*16384+8192);
    __builtin_amdgcn_s_setprio(1);
    #pragma unroll
    for (int mi=0;mi<4;mi++)
      acc[mi][0] = __builtin_amdgcn_mfma_f32_16x16x32_bf16(a[mi], b[0], acc[mi][0], 0,0,0);
    __builtin_amdgcn_s_setprio(0);
    asm volatile("s_waitcnt lgkmcnt(0)" ::: "memory");
    asm volatile("s_waitcnt vmcnt(4)" ::: "memory");
    __builtin_amdgcn_s_barrier();
    short8 na[4], nb0, nb1;
    nb0 = RDB1(nb, wc+fr);
    nb1 = RDB1(nb, wc+16+fr);
    #pragma unroll
    for (int mi=0;mi<4;mi++) na[mi] = RDA1(nb, wr+mi*16+fr);
    __builtin_amdgcn_s_setprio(1);
    #pragma unroll
    for (int mi=0;mi<4;mi++)
      acc[mi][1] = __builtin_amdgcn_mfma_f32_16x16x32_bf16(a[mi], b[1], acc[mi][1], 0,0,0);
    __builtin_amdgcn_s_setprio(0);
    b[0] = nb0; b[1] = nb1;
    #pragma unroll
    for (int mi=0;mi<4;mi++) a[mi] = na[mi];
  }
  #undef STG1
  #undef RDA1
  #undef RDB1

  #pragma unroll
  for (int mi=0;mi<4;mi++)
    #pragma unroll
    for (int ni=0;ni<2;ni++){
      int col = n0 + wc + ni*16 + fr;
      float bi = bias[col];
      #pragma unroll
      for (int r=0;r<4;r++){
        int row = m0 + wr + mi*16 + fq*4 + r;
        float vv = acc[mi][ni][r] + bi;
        if (EPI==1){
          size_t idx = (size_t)row*N + col;
          outb[idx] = f2bf(vv + bf2f(resb[idx]));
        } else {  // EPI==5
          if (col < 1024)      outb [(size_t)row*H + col]            = f2bf(vv);
          else if (col < 1280) outb2[(size_t)row*KVD + (col-1024)]   = f2bf(vv);
          else                 outb3[(size_t)(col-1280)*MROWS + row] = f2bf(vv);
        }
      }
    }
}

// ---------------- GEMM 256x256, 8 waves, BK=32, 16x16 MFMA, 4-sub-phase pipeline ----
// (r11 variant — best measured: ~300 µs head, MfmaUtil 39%, VGPR 108)
// EPI: 2 = +bias+gelu -> bf16 | 3 = plain -> f32
template<int EPI>
__global__ __launch_bounds__(512, 2) void gemm256(
    const unsigned short* __restrict__ A, const unsigned short* __restrict__ Bt,
    const float* __restrict__ bias, float* __restrict__ outf,
    unsigned short* __restrict__ outb, int N, int K)
{
  __shared__ __align__(16) char lds[131072];  // 4 bufs x (A 16K + B 16K)
  const int tid = threadIdx.x;
  const int lane = tid & 63, wid = tid >> 6;
  const int wrr = wid >> 2, wc = wid & 3;
  const int fr = lane & 15, fq = lane >> 4;
  const int m0 = blockIdx.x*256, n0 = blockIdx.y*256;
  const int nt = K >> 5;
  f32x4 acc[8][4] = {};

  #define STG(PTR, baserow, kt, ldsoff) do {                                    \
    _Pragma("unroll")                                                           \
    for (int c=0;c<2;c++){                                                      \
      int rr = c*128 + (tid>>2);                                                \
      int ss = (tid&3) ^ ((rr>>1)&3);                                           \
      __builtin_amdgcn_global_load_lds(                                         \
        (const __attribute__((address_space(1))) void*)((PTR) + (size_t)((baserow)+rr)*K + (kt)*32 + ss*8), \
        (__attribute__((address_space(3))) void*)(lds + (ldsoff) + c*8192 + wid*1024), 16, 0, 0); \
    }                                                                           \
  } while(0)
  #define RDA(buf,row) (*(const short8*)(lds + (buf)*32768 + (row)*64 + ((fq ^ (((row)>>1)&3))*16)))
  #define RDB(buf,row) (*(const short8*)(lds + (buf)*32768 + 16384 + (row)*64 + ((fq ^ (((row)>>1)&3))*16)))

  STG(A,  m0, 0, 0);      STG(Bt, n0, 0, 16384);
  STG(A,  m0, 1, 32768);  STG(Bt, n0, 1, 32768+16384);
  STG(A,  m0, 2, 65536);  STG(Bt, n0, 2, 65536+16384);
  asm volatile("s_waitcnt vmcnt(8)" ::: "memory");
  __builtin_amdgcn_s_barrier();

  short8 a[4], b2[2];
  short8 bA = RDB(0, wc*64+fr);
  short8 bB = RDB(0, wc*64+16+fr);
  #pragma unroll
  for (int mi=0;mi<4;mi++) a[mi] = RDA(0, wrr*128+mi*16+fr);

  for (int t = 0; t < nt; ++t){
    const int buf = t & 3;
    const int s3 = (t+3) & 3;
    const int nb = (t+1) & 3;
    const int t3 = (t+3 < nt) ? t+3 : nt-1;
    short8 ah[4];
    #pragma unroll
    for (int mi=0;mi<4;mi++) ah[mi] = RDA(buf, wrr*128+(4+mi)*16+fr);
    b2[0] = RDB(buf, wc*64+32+fr);
    b2[1] = RDB(buf, wc*64+48+fr);
    STG(A, m0, t3, s3*32768);
    __builtin_amdgcn_s_setprio(1);
    #pragma unroll
    for (int mi=0;mi<4;mi++){
      acc[mi][0] = __builtin_amdgcn_mfma_f32_16x16x32_bf16(a[mi], bA, acc[mi][0], 0,0,0);
      acc[mi][1] = __builtin_amdgcn_mfma_f32_16x16x32_bf16(a[mi], bB, acc[mi][1], 0,0,0);
    }
    __builtin_amdgcn_s_setprio(0);
    STG(Bt, n0, t3, s3*32768+16384);
    __builtin_amdgcn_s_setprio(1);
    #pragma unroll
    for (int mi=0;mi<4;mi++){
      acc[4+mi][0] = __builtin_amdgcn_mfma_f32_16x16x32_bf16(ah[mi], bA, acc[4+mi][0], 0,0,0);
      acc[4+mi][1] = __builtin_amdgcn_mfma_f32_16x16x32_bf16(ah[mi], bB, acc[4+mi][1], 0,0,0);
    }
    __builtin_amdgcn_s_setprio(0);
    asm volatile("s_waitcnt lgkmcnt(0)" ::: "memory");
    asm volatile("s_waitcnt vmcnt(8)" ::: "memory");
    __builtin_amdgcn_s_barrier();
    short8 nbA = RDB(nb, wc*64+fr);
    short8 nbB = RDB(nb, wc*64+16+fr);
    short8 na[4];
    #pragma unroll
    for (int mi=0;mi<4;mi++) na[mi] = RDA(nb, wrr*128+mi*16+fr);
    __builtin_amdgcn_s_setprio(1);
    #pragma unroll
    for (int mi=0;mi<4;mi++){
      acc[mi][2] = __builtin_amdgcn_mfma_f32_16x16x32_bf16(a[mi], b2[0], acc[mi][2], 0,0,0);
      acc[mi][3] = __builtin_amdgcn_mfma_f32_16x16x32_bf16(a[mi], b2[1], acc[mi][3], 0,0,0);
    }
    __builtin_amdgcn_s_setprio(0);
    __builtin_amdgcn_s_setprio(1);
    #pragma unroll
    for (int mi=0;mi<4;mi++){
      acc[4+mi][2] = __builtin_amdgcn_mfma_f32_16x16x32_bf16(ah[mi], b2[0], acc[4+mi][2], 0,0,0);
      acc[4+mi][3] = __builtin_amdgcn_mfma_f32_16x16x32_bf16(ah[mi], b2[1], acc[4+mi][3], 0,0,0);
    }
    __builtin_amdgcn_s_setprio(0);
    bA = nbA; bB = nbB;
    #pragma unroll
    for (int mi=0;mi<4;mi++) a[mi] = na[mi];
  }
  #undef STG
  #undef RDA
  #undef RDB

  #pragma unroll
  for (int mi=0; mi<8; mi++)
    #pragma unroll
    for (int ni=0; ni<4; ni++){
      int col = n0 + wc*64 + ni*16 + fr;
      float bi = (EPI==3) ? 0.0f : bias[col];
      #pragma unroll
      for (int r=0; r<4; r++){
        int row = m0 + wrr*128 + mi*16 + fq*4 + r;
        float vv = acc[mi][ni][r] + bi;
        size_t idx = (size_t)row*N + col;
        if (EPI==3) outf[idx] = vv;
        else        outb[idx] = f2bf(0.5f*vv*(1.0f+erff(vv*0.70710678118f)));
      }
    }
}

// ---------------- flash attention v4 ----------------
#define LOG2E 1.4426950408889634f
__global__ __launch_bounds__(256) void attn_kernel(
    const unsigned short* __restrict__ q, const unsigned short* __restrict__ kptr,
    const unsigned short* __restrict__ vt, const float* __restrict__ mask,
    unsigned short* __restrict__ o)
{
  __shared__ char Pbuf[4][4096];
  int tid = threadIdx.x;
  int lane = tid & 63, wid = tid >> 6;
  int fr = lane & 15, fq = lane >> 4, fo = fq*8;
  int h = blockIdx.y, b = blockIdx.z, g = h >> 2;
  int qcol = h*HD, kcol = g*HD;
  int qbase = b*SS + blockIdx.x*128 + wid*32;
  char* Pl = Pbuf[wid];
  int swz = (fr & 7) << 4;

  short8 bq[2][2];
  #pragma unroll
  for (int h2=0; h2<2; h2++){
    const unsigned short* qrow = q + (size_t)(qbase + h2*16 + fr)*H + qcol;
    bq[h2][0] = *(const short8*)(qrow + fo);
    bq[h2][1] = *(const short8*)(qrow + 32 + fo);
  }

  f32x4 oacc[2][4] = {};
  float mrun[2] = {-1e30f, -1e30f}, lsum[2] = {0.f, 0.f};
  const float sc2 = 0.125f * LOG2E;

  const unsigned short* kp[4];
  #pragma unroll
  for (int f=0; f<4; f++) kp[f] = kptr + (size_t)(b*SS + f*16 + fr)*KVD + kcol + fo;
  const unsigned short* vp[4];
  #pragma unroll
  for (int dc=0; dc<4; dc++) vp[dc] = vt + (size_t)(kcol + dc*16 + fr)*MROWS + b*SS + fo;
  const float* mp = mask + b*SS + fq*4;

  short8 kaA[4][2], kaB[4][2];
  #pragma unroll
  for (int f=0; f<4; f++){
    kaA[f][0] = *(const short8*)(kp[f]);
    kaA[f][1] = *(const short8*)(kp[f] + 32);
    kp[f] += 64*KVD;
  }

#define ATTN_STEP(KA, KB, PF) do {                                             \
    f32x4 mkv[4];                                                              \
    _Pragma("unroll")                                                          \
    for (int f=0; f<4; f++) mkv[f] = *(const f32x4*)(mp + f*16);               \
    short8 va[4][2];                                                           \
    _Pragma("unroll")                                                          \
    for (int dc=0; dc<4; dc++){                                                \
      va[dc][0] = *(const short8*)(vp[dc]);                                    \
      va[dc][1] = *(const short8*)(vp[dc] + 32);                               \
    }                                                                          \
    f32x4 sf[2][4] = {};                                                       \
    __builtin_amdgcn_s_setprio(1);                                             \
    _Pragma("unroll")                                                          \
    for (int h2=0; h2<2; h2++)                                                 \
      _Pragma("unroll")                                                        \
      for (int f=0; f<4; f++){                                                 \
        sf[h2][f] = __builtin_amdgcn_mfma_f32_16x16x32_bf16(KA[f][0], bq[h2][0], sf[h2][f],0,0,0); \
        sf[h2][f] = __builtin_amdgcn_mfma_f32_16x16x32_bf16(KA[f][1], bq[h2][1], sf[h2][f],0,0,0); \
      }                                                                        \
    __builtin_amdgcn_s_setprio(0);                                             \
    if (PF){                                                                   \
      _Pragma("unroll")                                                        \
      for (int f=0; f<4; f++){                                                 \
        KB[f][0] = *(const short8*)(kp[f]);                                    \
        KB[f][1] = *(const short8*)(kp[f] + 32);                               \
        kp[f] += 64*KVD;                                                       \
      }                                                                        \
    }                                                                          \
    _Pragma("unroll")                                                          \
    for (int f=0; f<4; f++){                                                   \
      _Pragma("unroll")                                                        \
      for (int r=0; r<4; r++){                                                 \
        float m2 = mkv[f][r]*LOG2E;                                            \
        sf[0][f][r] = sf[0][f][r]*sc2 + m2;                                    \
        sf[1][f][r] = sf[1][f][r]*sc2 + m2;                                    \
      }                                                                        \
    }                                                                          \
    float pm[2];                                                               \
    _Pragma("unroll")                                                          \
    for (int h2=0; h2<2; h2++){                                                \
      float a0 = fmaxf(fmaxf(sf[h2][0][0],sf[h2][0][1]), fmaxf(sf[h2][0][2],sf[h2][0][3])); \
      float a1 = fmaxf(fmaxf(sf[h2][1][0],sf[h2][1][1]), fmaxf(sf[h2][1][2],sf[h2][1][3])); \
      float a2 = fmaxf(fmaxf(sf[h2][2][0],sf[h2][2][1]), fmaxf(sf[h2][2][2],sf[h2][2][3])); \
      float a3 = fmaxf(fmaxf(sf[h2][3][0],sf[h2][3][1]), fmaxf(sf[h2][3][2],sf[h2][3][3])); \
      float p = fmaxf(fmaxf(a0,a1), fmaxf(a2,a3));                             \
      p = fmaxf(p, __shfl_xor(p, 16));                                         \
      p = fmaxf(p, __shfl_xor(p, 32));                                         \
      pm[h2] = p;                                                              \
    }                                                                          \
    if (!__all(pm[0] <= mrun[0]+8.f && pm[1] <= mrun[1]+8.f)){                 \
      float al[2];                                                             \
      _Pragma("unroll")                                                        \
      for (int h2=0; h2<2; h2++){                                              \
        float mn = fmaxf(mrun[h2], pm[h2]);                                    \
        al[h2] = __builtin_amdgcn_exp2f(mrun[h2]-mn);                          \
        mrun[h2] = mn;                                                         \
        lsum[h2] *= al[h2];                                                    \
      }                                                                        \
      _Pragma("unroll")                                                        \
      for (int r=0; r<4; r++){                                                 \
        float altl = __shfl(al[0], fq*4+r);                                    \
        float alth = __shfl(al[1], fq*4+r);                                    \
        _Pragma("unroll")                                                      \
        for (int dc=0; dc<4; dc++){ oacc[0][dc][r]*=altl; oacc[1][dc][r]*=alth; } \
      }                                                                        \
    }                                                                          \
    _Pragma("unroll")                                                          \
    for (int h2=0; h2<2; h2++){                                                \
      float ps = 0.f;                                                          \
      _Pragma("unroll")                                                        \
      for (int f=0; f<4; f++)                                                  \
        _Pragma("unroll")                                                      \
        for (int r=0; r<4; r++){                                               \
          float e = __builtin_amdgcn_exp2f(sf[h2][f][r]-mrun[h2]);             \
          sf[h2][f][r] = e; ps += e;                                           \
        }                                                                      \
      ps += __shfl_xor(ps, 16);                                                \
      ps += __shfl_xor(ps, 32);                                                \
      lsum[h2] += ps;                                                          \
    }                                                                          \
    _Pragma("unroll")                                                          \
    for (int h2=0; h2<2; h2++){                                                \
      int prow = h2*16 + fr;                                                   \
      _Pragma("unroll")                                                        \
      for (int f=0; f<4; f++){                                                 \
        u32x2 pw;                                                              \
        pw[0] = cvt_pk_bf16(sf[h2][f][0], sf[h2][f][1]);                       \
        pw[1] = cvt_pk_bf16(sf[h2][f][2], sf[h2][f][3]);                       \
        *(u32x2*)(Pl + prow*128 + ((f*32 + fq*8) ^ swz)) = pw;                 \
      }                                                                        \
    }                                                                          \
    __builtin_amdgcn_s_setprio(1);                                             \
    _Pragma("unroll")                                                          \
    for (int h2=0; h2<2; h2++){                                                \
      int prow = h2*16 + fr;                                                   \
      _Pragma("unroll")                                                        \
      for (int gs=0; gs<2; gs++){                                              \
        short8 pa = *(const short8*)(Pl + prow*128 + ((gs*64 + fq*16) ^ swz)); \
        _Pragma("unroll")                                                      \
        for (int dc=0; dc<4; dc++)                                             \
          oacc[h2][dc] = __builtin_amdgcn_mfma_f32_16x16x32_bf16(pa, va[dc][gs], oacc[h2][dc],0,0,0); \
      }                                                                        \
    }                                                                          \
    __builtin_amdgcn_s_setprio(0);                                             \
    _Pragma("unroll")                                                          \
    for (int dc=0; dc<4; dc++) vp[dc] += 64;                                   \
    mp += 64;                                                                  \
  } while(0)

  for (int it = 0; it < SS/128 - 1; ++it){
    ATTN_STEP(kaA, kaB, 1);
    ATTN_STEP(kaB, kaA, 1);
  }
  ATTN_STEP(kaA, kaB, 1);
  ATTN_STEP(kaB, kaA, 0);
#undef ATTN_STEP

  #pragma unroll
  for (int h2=0; h2<2; h2++){
    float lt[4];
    #pragma unroll
    for (int r=0; r<4; r++) lt[r] = __shfl(lsum[h2], fq*4+r);
    #pragma unroll
    for (int dc=0; dc<4; dc++)
      #pragma unroll
      for (int r=0; r<4; r++){
        int row = qbase + h2*16 + fq*4 + r;
        o[(size_t)row*H + qcol + dc*16 + fr] = f2bf(oacc[h2][dc][r] / lt[r]);
      }
  }
}

extern "C" void kernel_launch(void* const* d_in, const int* in_sizes, int n_in,
                              void* d_out, int out_size, void* d_ws, size_t ws_size,
                              hipStream_t stream)
{
  const int*   ids  = (const int*)  d_in[0];
  const float* mask = (const float*)d_in[1];
  const float* tok  = (const float*)d_in[2];
  const float* pos  = (const float*)d_in[3];
  const float* Wq   = (const float*)d_in[4];
  const float* bq   = (const float*)d_in[5];
  const float* Wk   = (const float*)d_in[6];
  const float* bk   = (const float*)d_in[7];
  const float* Wv   = (const float*)d_in[8];
  const float* bv   = (const float*)d_in[9];
  const float* Wo   = (const float*)d_in[10];
  const float* bo   = (const float*)d_in[11];
  const float* W1   = (const float*)d_in[12];
  const float* b1   = (const float*)d_in[13];
  const float* W2   = (const float*)d_in[14];
  const float* b2   = (const float*)d_in[15];
  const float* ln1g = (const float*)d_in[16];
  const float* ln1b = (const float*)d_in[17];
  const float* ln2g = (const float*)d_in[18];
  const float* ln2b = (const float*)d_in[19];
  const float* lnfg = (const float*)d_in[20];
  const float* lnfb = (const float*)d_in[21];
  const float* Wh   = (const float*)d_in[22];
  float* out = (float*)d_out;

  char* ws = (char*)d_ws;
  unsigned short* x    = (unsigned short*)ws; ws += (size_t)MROWS*H*2;
  unsigned short* hb   = (unsigned short*)ws; ws += (size_t)MROWS*H*2;
  unsigned short* qb   = (unsigned short*)ws; ws += (size_t)MROWS*H*2;
  unsigned short* kb   = (unsigned short*)ws; ws += (size_t)MROWS*KVD*2;
  unsigned short* vtb  = (unsigned short*)ws; ws += (size_t)KVD*MROWS*2;
  unsigned short* ob   = (unsigned short*)ws; ws += (size_t)MROWS*H*2;
  unsigned short* f1   = (unsigned short*)ws; ws += (size_t)MROWS*FF*2;
  unsigned short* Wqkv = (unsigned short*)ws; ws += (size_t)LAYERS*QKVN*H*2;
  unsigned short* WoT  = (unsigned short*)ws; ws += (size_t)LAYERS*H*H*2;
  unsigned short* W1T  = (unsigned short*)ws; ws += (size_t)LAYERS*H*FF*2;
  unsigned short* W2T  = (unsigned short*)ws; ws += (size_t)LAYERS*H*FF*2;
  unsigned short* WhT  = (unsigned short*)ws; ws += (size_t)H*VOC*2;
  float*          bcat = (float*)ws;          ws += (size_t)LAYERS*QKVN*4;

  convT_kernel<<<dim3(H/64,   H/64,  LAYERS), 256, 0, stream>>>(Wq, Wqkv,          H,  H,   (size_t)H*H,   (size_t)QKVN*H);
  convT_kernel<<<dim3(KVD/64, H/64,  LAYERS), 256, 0, stream>>>(Wk, Wqkv + 1024*H, H,  KVD, (size_t)H*KVD, (size_t)QKVN*H);
  convT_kernel<<<dim3(KVD/64, H/64,  LAYERS), 256, 0, stream>>>(Wv, Wqkv + 1280*H, H,  KVD, (size_t)H*KVD, (size_t)QKVN*H);
  convT_kernel<<<dim3(H/64,   H/64,  LAYERS), 256, 0, stream>>>(Wo, WoT,           H,  H,   (size_t)H*H,   (size_t)H*H);
  convT_kernel<<<dim3(FF/64,  H/64,  LAYERS), 256, 0, stream>>>(W1, W1T,           H,  FF,  (size_t)H*FF,  (size_t)H*FF);
  convT_kernel<<<dim3(H/64,   FF/64, LAYERS), 256, 0, stream>>>(W2, W2T,           FF, H,   (size_t)FF*H,  (size_t)FF*H);
  convT_kernel<<<dim3(VOC/64, H/64,  1),      256, 0, stream>>>(Wh, WhT,           H,  VOC, 0, 0);
  bcat_kernel<<<LAYERS, 256, 0, stream>>>(bq, bk, bv, bcat);

  embed_kernel<<<MROWS, 256, 0, stream>>>(ids, tok, pos, x);
  for (int l=0; l<LAYERS; l++){
    ln_kernel<<<MROWS,256,0,stream>>>(x, ln1g + l*H, ln1b + l*H, hb);
    gemm_bt<5><<<dim3(MROWS/128, QKVN/128),512,0,stream>>>(hb, Wqkv + (size_t)l*QKVN*H, bcat + l*QKVN, nullptr, qb, kb, vtb, QKVN, H);
    attn_kernel<<<dim3(SS/128, NH, BB), 256, 0, stream>>>(qb, kb, vtb, mask, ob);
    gemm_bt<1><<<dim3(MROWS/128, H/128),  512,0,stream>>>(ob, WoT + (size_t)l*H*H,  bo + l*H,  x, x, nullptr, nullptr, H, H);
    ln_kernel<<<MROWS,256,0,stream>>>(x, ln2g + l*H, ln2b + l*H, hb);
    gemm256<2><<<dim3(MROWS/256, FF/256), 512,0,stream>>>(hb, W1T + (size_t)l*H*FF, b1 + l*FF, nullptr, f1, FF, H);
    gemm_bt<1><<<dim3(MROWS/128, H/128),  512,0,stream>>>(f1, W2T + (size_t)l*H*FF, b2 + l*H,  x, x, nullptr, nullptr, H, FF);
  }
  ln_kernel<<<MROWS,256,0,stream>>>(x, lnfg, lnfb, hb);
  gemm256<3><<<dim3(MROWS/256, VOC/256), 512,0,stream>>>(hb, WhT, nullptr, out, nullptr, VOC, H);
}